// Round 1
// baseline (1962.630 us; speedup 1.0000x reference)
//
#include <hip/hip_runtime.h>

#define NN 100000
#define EE 1600000
#define BB 64

__device__ __forceinline__ unsigned fmap(float f) {
  unsigned u = __float_as_uint(f);
  return (u & 0x80000000u) ? ~u : (u | 0x80000000u);
}
__device__ __forceinline__ float funmap(unsigned m) {
  unsigned u = (m & 0x80000000u) ? (m ^ 0x80000000u) : ~m;
  return __uint_as_float(u);
}

// ---------------- CSR build (by dst) ----------------
__global__ void k_hist(const int* __restrict__ dst, int* __restrict__ counts) {
  int i = blockIdx.x * blockDim.x + threadIdx.x;
  if (i < EE) atomicAdd(&counts[dst[i]], 1);
}

__global__ void k_scan(const int* __restrict__ counts, int* __restrict__ rowptr) {
  __shared__ int buf[1024];
  __shared__ int carry_s;
  if (threadIdx.x == 0) { carry_s = 0; rowptr[0] = 0; }
  __syncthreads();
  for (int base = 0; base < NN; base += 1024) {
    int i = base + threadIdx.x;
    int v = (i < NN) ? counts[i] : 0;
    buf[threadIdx.x] = v;
    __syncthreads();
    for (int off = 1; off < 1024; off <<= 1) {
      int t = (threadIdx.x >= off) ? buf[threadIdx.x - off] : 0;
      __syncthreads();
      buf[threadIdx.x] += t;
      __syncthreads();
    }
    int inc = buf[threadIdx.x] + carry_s;
    if (i < NN) rowptr[i + 1] = inc;
    __syncthreads();
    if (threadIdx.x == 1023) carry_s = inc;
    __syncthreads();
  }
}

__global__ void k_scatter(const int* __restrict__ src, const int* __restrict__ dst,
                          int* __restrict__ cursor, int* __restrict__ adjsrc) {
  int i = blockIdx.x * blockDim.x + threadIdx.x;
  if (i < EE) {
    int pos = atomicAdd(&cursor[dst[i]], 1);
    adjsrc[pos] = src[i];
  }
}

// ---------------- softmax aggregation (one wave per node, lane = channel) ----------------
template<int F>
__global__ void k_agg(const float* __restrict__ xin, const int* __restrict__ rowptr,
                      const int* __restrict__ adjsrc, float* __restrict__ out) {
  int wid = (blockIdx.x * blockDim.x + threadIdx.x) >> 6;
  int lane = threadIdx.x & 63;
  if (wid >= NN) return;
  int s = rowptr[wid], e = rowptr[wid + 1];
  float m = -INFINITY, den = 0.f, num = 0.f;
  for (int i = s; i < e; ++i) {
    int sn = adjsrc[i];
    float v = (F == 64 || lane < F) ? xin[sn * F + lane] : 0.f;
    v = fmaxf(v, 0.f) + 1e-7f;           // msg = relu(x_j) + eps
    float mn = fmaxf(m, v);
    float e1 = __expf(m - mn);           // exp(-inf)=0 handles first iter
    float e2 = __expf(v - mn);
    den = den * e1 + e2;
    num = num * e1 + v * e2;
    m = mn;
  }
  if (F == 64 || lane < F) {
    float a = num / (den + 1e-16f);      // = sum(msg*alpha)
    out[wid * F + lane] = a + xin[wid * F + lane];  // root residual
  }
}

// ---------------- per-node GEMM: T[node] = A[node] @ W + bias ----------------
template<int FK, int FN, int CHUNK>
__global__ void k_gemm(const float* __restrict__ A, const float* __restrict__ W,
                       const float* __restrict__ bias, float* __restrict__ T) {
  int node = blockIdx.x * blockDim.x + threadIdx.x;
  if (node >= NN) return;
  float a[FK];
#pragma unroll
  for (int c = 0; c < FK; ++c) a[c] = A[node * FK + c];
#pragma unroll
  for (int k0 = 0; k0 < FN; k0 += CHUNK) {
    float acc[CHUNK];
#pragma unroll
    for (int j = 0; j < CHUNK; ++j) acc[j] = bias[k0 + j];
    for (int c = 0; c < FK; ++c) {
      float ac = a[c];
#pragma unroll
      for (int j = 0; j < CHUNK; ++j) acc[j] += ac * W[c * FN + k0 + j];
    }
#pragma unroll
    for (int j = 0; j < CHUNK; ++j) T[node * FN + k0 + j] = acc[j];
  }
}

// ---------------- BN statistics ----------------
template<int FN>
__global__ void k_stats(const float* __restrict__ T, float* __restrict__ sums,
                        float* __restrict__ sumsq) {
  __shared__ float ls[FN], lsq[FN];
  for (int i = threadIdx.x; i < FN; i += blockDim.x) { ls[i] = 0.f; lsq[i] = 0.f; }
  __syncthreads();
  int total = NN * FN;
  for (int i = blockIdx.x * blockDim.x + threadIdx.x; i < total; i += gridDim.x * blockDim.x) {
    float v = T[i];
    int c = i % FN;
    atomicAdd(&ls[c], v);
    atomicAdd(&lsq[c], v * v);
  }
  __syncthreads();
  for (int i = threadIdx.x; i < FN; i += blockDim.x) {
    atomicAdd(&sums[i], ls[i]);
    atomicAdd(&sumsq[i], lsq[i]);
  }
}

template<int FN>
__global__ void k_bnfin(const float* __restrict__ sums, const float* __restrict__ sumsq,
                        float* __restrict__ mu, float* __restrict__ rstd) {
  int c = threadIdx.x;
  if (c < FN) {
    float m = sums[c] * (1.0f / NN);
    float v = sumsq[c] * (1.0f / NN) - m * m;
    mu[c] = m;
    rstd[c] = rsqrtf(fmaxf(v, 0.f) + 1e-5f);
  }
}

// ---------------- BN apply + relu + GEMM2 (+ residual update of h) ----------------
template<int FK, int FN, int MODE>  // MODE 0: H = relu(val) (layer0); MODE 1: H += val
__global__ void k_bn_gemm2(const float* __restrict__ T, const float* __restrict__ mu,
                           const float* __restrict__ rstd, const float* __restrict__ gamma,
                           const float* __restrict__ beta, const float* __restrict__ W2,
                           const float* __restrict__ b2, float* __restrict__ H) {
  int node = blockIdx.x * blockDim.x + threadIdx.x;
  if (node >= NN) return;
  float h1[FK];
#pragma unroll
  for (int c = 0; c < FK; ++c) {
    float v = T[node * FK + c];
    h1[c] = fmaxf((v - mu[c]) * rstd[c] * gamma[c] + beta[c], 0.f);
  }
#pragma unroll
  for (int k0 = 0; k0 < FN; k0 += 16) {
    float acc[16];
#pragma unroll
    for (int j = 0; j < 16; ++j) acc[j] = b2[k0 + j];
    for (int c = 0; c < FK; ++c) {
      float hc = h1[c];
#pragma unroll
      for (int j = 0; j < 16; ++j) acc[j] += hc * W2[c * FN + k0 + j];
    }
#pragma unroll
    for (int j = 0; j < 16; ++j) {
      int idx = node * FN + k0 + j;
      if (MODE == 0) H[idx] = fmaxf(acc[j], 0.f);
      else H[idx] += acc[j];
    }
  }
}

// ---------------- misc ----------------
__global__ void k_relu4(const float4* __restrict__ in, float4* __restrict__ out, int n4) {
  int i = blockIdx.x * blockDim.x + threadIdx.x;
  if (i < n4) {
    float4 v = in[i];
    v.x = fmaxf(v.x, 0.f); v.y = fmaxf(v.y, 0.f);
    v.z = fmaxf(v.z, 0.f); v.w = fmaxf(v.w, 0.f);
    out[i] = v;
  }
}

__global__ void k_pool_init(unsigned* gmax) {
  int i = blockIdx.x * blockDim.x + threadIdx.x;
  if (i < BB * 64) gmax[i] = 0x007FFFFFu;  // fmap(-inf)
}

__global__ void k_pool(const float* __restrict__ h, const int* __restrict__ batch,
                       unsigned* __restrict__ gmax) {
  __shared__ unsigned lmax[BB * 64];
  for (int i = threadIdx.x; i < BB * 64; i += blockDim.x) lmax[i] = 0x007FFFFFu;
  __syncthreads();
  int total = NN * 64;
  for (int i = blockIdx.x * blockDim.x + threadIdx.x; i < total; i += gridDim.x * blockDim.x) {
    int node = i >> 6, c = i & 63;
    atomicMax(&lmax[(batch[node] << 6) + c], fmap(h[i]));
  }
  __syncthreads();
  for (int i = threadIdx.x; i < BB * 64; i += blockDim.x) atomicMax(&gmax[i], lmax[i]);
}

__global__ void k_final(const unsigned* __restrict__ gmax, const float* __restrict__ w1,
                        const float* __restrict__ b1, const float* __restrict__ w2,
                        const float* __restrict__ b2, float* __restrict__ out) {
  int b = blockIdx.x;
  __shared__ float g[64], hid[64];
  int t = threadIdx.x;
  if (t < 64) {
    float v = funmap(gmax[b * 64 + t]);
    if (v == -INFINITY) v = 0.f;
    g[t] = v;
  }
  __syncthreads();
  if (t < 64) {
    float acc = b1[t];
    for (int c = 0; c < 64; ++c) acc += g[c] * w1[c * 64 + t];
    hid[t] = fmaxf(acc, 0.f);
  }
  __syncthreads();
  if (t < 80) {
    float acc = b2[t];
    for (int c = 0; c < 64; ++c) acc += hid[c] * w2[c * 80 + t];
    out[b * 80 + t] = acc;
  }
}

extern "C" void kernel_launch(void* const* d_in, const int* in_sizes, int n_in,
                              void* d_out, int out_size, void* d_ws, size_t ws_size,
                              hipStream_t stream) {
  const float* x       = (const float*)d_in[0];
  const int*   ei      = (const int*)d_in[1];
  const int*   batch   = (const int*)d_in[2];
  const float* cin_w1  = (const float*)d_in[3];
  const float* cin_b1  = (const float*)d_in[4];
  const float* cin_g1  = (const float*)d_in[5];
  const float* cin_be1 = (const float*)d_in[6];
  const float* cin_w2  = (const float*)d_in[7];
  const float* cin_b2  = (const float*)d_in[8];
  const float* L_w1    = (const float*)d_in[9];
  const float* L_b1    = (const float*)d_in[10];
  const float* L_g1    = (const float*)d_in[11];
  const float* L_be1   = (const float*)d_in[12];
  const float* L_w2    = (const float*)d_in[13];
  const float* L_b2    = (const float*)d_in[14];
  const float* mlp_w1  = (const float*)d_in[15];
  const float* mlp_b1  = (const float*)d_in[16];
  const float* mlp_w2  = (const float*)d_in[17];
  const float* mlp_b2  = (const float*)d_in[18];

  char* ws = (char*)d_ws;
  size_t off = 0;
  auto alloc = [&](size_t bytes) -> void* {
    void* p = ws + off;
    off = (off + bytes + 255) & ~(size_t)255;
    return p;
  };
  float*    h      = (float*)alloc((size_t)NN * 64 * 4);
  float*    t      = (float*)alloc((size_t)NN * 128 * 4);  // also reused as xr (first half)
  float*    xr     = t;                                    // relu(h); dead before t is written
  float*    agg    = (float*)alloc((size_t)NN * 64 * 4);
  int*      rowptr = (int*)alloc((size_t)(NN + 1) * 4);
  int*      cursor = (int*)alloc((size_t)NN * 4);          // also counts
  int*      adjsrc = (int*)alloc((size_t)EE * 4);
  float*    sums   = (float*)alloc(128 * 4);
  float*    sumsq  = (float*)alloc(128 * 4);
  float*    mu     = (float*)alloc(128 * 4);
  float*    rstd   = (float*)alloc(128 * 4);
  unsigned* gmax   = (unsigned*)alloc((size_t)BB * 64 * 4);
  (void)ws_size; (void)in_sizes; (void)n_in; (void)out_size;

  const int* srcp = ei;
  const int* dstp = ei + EE;

  // CSR build
  hipMemsetAsync(cursor, 0, (size_t)NN * 4, stream);
  k_hist<<<(EE + 255) / 256, 256, 0, stream>>>(dstp, cursor);
  k_scan<<<1, 1024, 0, stream>>>(cursor, rowptr);
  hipMemcpyAsync(cursor, rowptr, (size_t)NN * 4, hipMemcpyDeviceToDevice, stream);
  k_scatter<<<(EE + 255) / 256, 256, 0, stream>>>(srcp, dstp, cursor, adjsrc);

  // Layer 0: GENConv(x[N,6]) -> h[N,64], h = relu(...)
  k_agg<6><<<NN / 4, 256, 0, stream>>>(x, rowptr, adjsrc, agg);
  k_gemm<6, 12, 12><<<(NN + 255) / 256, 256, 0, stream>>>(agg, cin_w1, cin_b1, t);
  hipMemsetAsync(sums, 0, 128 * 4, stream);
  hipMemsetAsync(sumsq, 0, 128 * 4, stream);
  k_stats<12><<<512, 256, 0, stream>>>(t, sums, sumsq);
  k_bnfin<12><<<1, 64, 0, stream>>>(sums, sumsq, mu, rstd);
  k_bn_gemm2<12, 64, 0><<<(NN + 255) / 256, 256, 0, stream>>>(t, mu, rstd, cin_g1, cin_be1,
                                                              cin_w2, cin_b2, h);

  // Layers 1..3: h += GENConv(relu(h))
  for (int i = 0; i < 3; ++i) {
    k_relu4<<<(NN * 16 + 255) / 256, 256, 0, stream>>>((const float4*)h, (float4*)xr, NN * 16);
    k_agg<64><<<NN / 4, 256, 0, stream>>>(xr, rowptr, adjsrc, agg);
    k_gemm<64, 128, 32><<<(NN + 255) / 256, 256, 0, stream>>>(agg, L_w1 + (size_t)i * 64 * 128,
                                                              L_b1 + i * 128, t);
    hipMemsetAsync(sums, 0, 128 * 4, stream);
    hipMemsetAsync(sumsq, 0, 128 * 4, stream);
    k_stats<128><<<512, 256, 0, stream>>>(t, sums, sumsq);
    k_bnfin<128><<<1, 128, 0, stream>>>(sums, sumsq, mu, rstd);
    k_bn_gemm2<128, 64, 1><<<(NN + 255) / 256, 256, 0, stream>>>(t, mu, rstd, L_g1 + i * 128,
                                                                 L_be1 + i * 128,
                                                                 L_w2 + (size_t)i * 128 * 64,
                                                                 L_b2 + i * 64, h);
  }

  // Global max pool + final MLP
  k_pool_init<<<(BB * 64 + 255) / 256, 256, 0, stream>>>(gmax);
  k_pool<<<128, 256, 0, stream>>>(h, batch, gmax);
  k_final<<<BB, 128, 0, stream>>>(gmax, mlp_w1, mlp_b1, mlp_w2, mlp_b2, (float*)d_out);
}

// Round 2
// 1180.233 us; speedup vs baseline: 1.6629x; 1.6629x over previous
//
#include <hip/hip_runtime.h>

#define NN 100000
#define EE 1600000
#define BB 64
#define NSCAN 98   // ceil(NN/1024)

__device__ __forceinline__ unsigned fmap(float f) {
  unsigned u = __float_as_uint(f);
  return (u & 0x80000000u) ? ~u : (u | 0x80000000u);
}
__device__ __forceinline__ float funmap(unsigned m) {
  unsigned u = (m & 0x80000000u) ? (m ^ 0x80000000u) : ~m;
  return __uint_as_float(u);
}

// ---------------- CSR build (by dst) ----------------
__global__ void k_hist(const int* __restrict__ dst, int* __restrict__ counts) {
  int i = blockIdx.x * blockDim.x + threadIdx.x;
  if (i < EE) atomicAdd(&counts[dst[i]], 1);
}

// block-local exclusive scan into rowptr, block totals into partials
__global__ void k_scan1(const int* __restrict__ counts, int* __restrict__ rowptr,
                        int* __restrict__ partials) {
  __shared__ int buf[1024];
  int i = blockIdx.x * 1024 + threadIdx.x;
  int v = (i < NN) ? counts[i] : 0;
  buf[threadIdx.x] = v;
  __syncthreads();
  for (int off = 1; off < 1024; off <<= 1) {
    int t = (threadIdx.x >= off) ? buf[threadIdx.x - off] : 0;
    __syncthreads();
    buf[threadIdx.x] += t;
    __syncthreads();
  }
  int incl = buf[threadIdx.x];
  if (i < NN) rowptr[i] = incl - v;  // block-local exclusive
  if (threadIdx.x == 1023) partials[blockIdx.x] = incl;
}

// scan the 98 partials (1 block, 128 threads); also init gmax
__global__ void k_scan2(const int* __restrict__ partials, int* __restrict__ poffs,
                        unsigned* __restrict__ gmax) {
  __shared__ int buf[128];
  int t = threadIdx.x;
  int v = (t < NSCAN) ? partials[t] : 0;
  buf[t] = v;
  __syncthreads();
  for (int off = 1; off < 128; off <<= 1) {
    int u = (t >= off) ? buf[t - off] : 0;
    __syncthreads();
    buf[t] += u;
    __syncthreads();
  }
  poffs[t] = buf[t] - v;  // exclusive
  for (int i = t; i < BB * 64; i += 128) gmax[i] = 0x007FFFFFu;  // fmap(-inf)
}

__global__ void k_scan3(int* __restrict__ rowptr, const int* __restrict__ poffs,
                        int* __restrict__ cursor) {
  int i = blockIdx.x * 1024 + threadIdx.x;
  if (i < NN) {
    int val = rowptr[i] + poffs[blockIdx.x];
    rowptr[i] = val;
    cursor[i] = val;
  }
  if (i == 0) rowptr[NN] = EE;
}

__global__ void k_scatter(const int* __restrict__ src, const int* __restrict__ dst,
                          int* __restrict__ cursor, int* __restrict__ adjsrc) {
  int i = blockIdx.x * blockDim.x + threadIdx.x;
  if (i < EE) {
    int pos = atomicAdd(&cursor[dst[i]], 1);
    adjsrc[pos] = src[i];
  }
}

// ---------------- softmax aggregation (one wave/node, lane=channel) ----------------
template<int F, int RELUIN>
__global__ __launch_bounds__(256) void k_agg(const float* __restrict__ xin,
                                             const int* __restrict__ rowptr,
                                             const int* __restrict__ adjsrc,
                                             float* __restrict__ out) {
  int w = __builtin_amdgcn_readfirstlane(threadIdx.x >> 6);
  int lane = threadIdx.x & 63;
  int wid = blockIdx.x * 4 + w;
  if (wid >= NN) return;
  int s = rowptr[wid], e = rowptr[wid + 1];
  bool act = (F == 64) || (lane < F);
  float den = 0.f, num = 0.f;
  int i = s;
  for (; i + 3 < e; i += 4) {
    int n0 = adjsrc[i], n1 = adjsrc[i + 1], n2 = adjsrc[i + 2], n3 = adjsrc[i + 3];
    float v0 = act ? xin[(size_t)n0 * F + lane] : 0.f;
    float v1 = act ? xin[(size_t)n1 * F + lane] : 0.f;
    float v2 = act ? xin[(size_t)n2 * F + lane] : 0.f;
    float v3 = act ? xin[(size_t)n3 * F + lane] : 0.f;
    float m0 = fminf(fmaxf(v0, 0.f) + 1e-7f, 80.f);
    float m1 = fminf(fmaxf(v1, 0.f) + 1e-7f, 80.f);
    float m2 = fminf(fmaxf(v2, 0.f) + 1e-7f, 80.f);
    float m3 = fminf(fmaxf(v3, 0.f) + 1e-7f, 80.f);
    float e0 = __expf(m0), e1 = __expf(m1), e2 = __expf(m2), e3 = __expf(m3);
    den += (e0 + e1) + (e2 + e3);
    num += (m0 * e0 + m1 * e1) + (m2 * e2 + m3 * e3);
  }
  for (; i < e; ++i) {
    int n0 = adjsrc[i];
    float v0 = act ? xin[(size_t)n0 * F + lane] : 0.f;
    float m0 = fminf(fmaxf(v0, 0.f) + 1e-7f, 80.f);
    float e0 = __expf(m0);
    den += e0;
    num += m0 * e0;
  }
  if (act) {
    float xr = xin[(size_t)wid * F + lane];
    float res = RELUIN ? fmaxf(xr, 0.f) : xr;
    out[(size_t)wid * F + lane] = num / (den + 1e-16f) + res;
  }
}

// ---------------- A^T A + column sums (for BN-from-covariance) ----------------
template<int F>
__global__ __launch_bounds__(256) void k_ata(const float* __restrict__ A,
                                             float* __restrict__ S,   // F*F
                                             float* __restrict__ cs) { // F
  int lane = threadIdx.x & 63;
  int w = __builtin_amdgcn_readfirstlane(threadIdx.x >> 6);
  bool act = (F == 64) || (lane < F);
  float Sloc[F];
#pragma unroll
  for (int c = 0; c < F; ++c) Sloc[c] = 0.f;
  float csloc = 0.f;
  int stride = gridDim.x * 4;
  for (int node = blockIdx.x * 4 + w; node < NN; node += stride) {
    float a = act ? A[(size_t)node * F + lane] : 0.f;
    csloc += a;
#pragma unroll
    for (int c = 0; c < F; ++c) {
      float ac = __shfl(a, c, 64);
      Sloc[c] += ac * a;
    }
  }
  __shared__ float ls[F * F];
  __shared__ float lcs[F];
  for (int idx = threadIdx.x; idx < F * F; idx += 256) ls[idx] = 0.f;
  if (threadIdx.x < F) lcs[threadIdx.x] = 0.f;
  __syncthreads();
  if (act) {
#pragma unroll
    for (int c = 0; c < F; ++c) atomicAdd(&ls[c * F + lane], Sloc[c]);
    atomicAdd(&lcs[lane], csloc);
  }
  __syncthreads();
  for (int idx = threadIdx.x; idx < F * F; idx += 256) atomicAdd(&S[idx], ls[idx]);
  if (threadIdx.x < F) atomicAdd(&cs[threadIdx.x], lcs[threadIdx.x]);
}

// ---------------- BN params from covariance: scale/shift per mid-channel ----------------
// ab[j] = rstd_j*gamma_j ; ab[FMID+j] = beta_j - mulin_j*scale_j
template<int FIN, int FMID>
__global__ void k_bnprep(const float* __restrict__ S, const float* __restrict__ cs,
                         const float* __restrict__ Wm, const float* __restrict__ bm,
                         const float* __restrict__ gamma, const float* __restrict__ beta,
                         float* __restrict__ ab) {
  int j = blockIdx.x;
  int lane = threadIdx.x;
  bool act = (FIN == 64) || (lane < FIN);
  float wj = act ? Wm[lane * FMID + j] : 0.f;
  float mb = act ? cs[lane] * (1.f / NN) : 0.f;
  float t = mb * wj;
#pragma unroll
  for (int off = 32; off; off >>= 1) t += __shfl_xor(t, off, 64);
  float mulin = t;
  float acc = 0.f;
  for (int c = 0; c < FIN; ++c) {
    float sv = act ? S[c * FIN + lane] : 0.f;
    float p = sv * wj;
#pragma unroll
    for (int off = 32; off; off >>= 1) p += __shfl_xor(p, off, 64);
    acc += p * __shfl(wj, c, 64);
  }
  if (lane == 0) {
    float var = acc * (1.f / NN) - mulin * mulin;
    float rstd = rsqrtf(fmaxf(var, 0.f) + 1e-5f);
    float sc = rstd * gamma[j];
    ab[j] = sc;
    ab[FMID + j] = beta[j] - mulin * sc;
  }
}

// ---------------- fused GEMM1 + BN + relu + GEMM2 + residual ----------------
template<int FIN, int FMID, int FOUT, int MODE>  // MODE 0: H=relu(out); 1: H+=out
__global__ __launch_bounds__(256) void k_layer(const float* __restrict__ A,
                                               const float* __restrict__ Wm,
                                               const float* __restrict__ ab,
                                               const float* __restrict__ W2,
                                               const float* __restrict__ b2,
                                               float* __restrict__ H) {
  constexpr int SA = FIN + 1;
  constexpr int SM = FMID + 1;
  constexpr int MW = FMID / 4;
  constexpr int OW = FOUT / 4;
  __shared__ float lA[64 * SA];
  __shared__ float lH[64 * SM];
  int tid = threadIdx.x;
  int lane = tid & 63;
  int w = __builtin_amdgcn_readfirstlane(tid >> 6);
  int nbase = blockIdx.x * 64;
  for (int e = tid; e < 64 * FIN; e += 256) {
    int nl = e / FIN, c = e - nl * FIN;
    int node = nbase + nl;
    lA[nl * SA + c] = (node < NN) ? A[(size_t)node * FIN + c] : 0.f;
  }
  __syncthreads();
  // phase 1: mid = A @ Wm (this wave's MW channels), then BN affine + relu -> LDS
  float acc[MW];
#pragma unroll
  for (int j = 0; j < MW; ++j) acc[j] = 0.f;
#pragma unroll 4
  for (int c = 0; c < FIN; ++c) {
    float a = lA[lane * SA + c];
#pragma unroll
    for (int j = 0; j < MW; ++j) acc[j] += a * Wm[c * FMID + w * MW + j];
  }
#pragma unroll
  for (int j = 0; j < MW; ++j) {
    float sc = ab[w * MW + j];
    float sh = ab[FMID + w * MW + j];
    lH[lane * SM + w * MW + j] = fmaxf(acc[j] * sc + sh, 0.f);
  }
  __syncthreads();
  // phase 2: out = h1 @ W2 + b2 (this wave's OW channels)
  float acc2[OW];
#pragma unroll
  for (int j = 0; j < OW; ++j) acc2[j] = b2[w * OW + j];
#pragma unroll 4
  for (int c = 0; c < FMID; ++c) {
    float hv = lH[lane * SM + c];
#pragma unroll
    for (int j = 0; j < OW; ++j) acc2[j] += hv * W2[c * FOUT + w * OW + j];
  }
  int node = nbase + lane;
  if (node < NN) {
    size_t base = (size_t)node * FOUT + w * OW;
    if (MODE == 0) {
#pragma unroll
      for (int j = 0; j < OW; ++j) H[base + j] = fmaxf(acc2[j], 0.f);
    } else {
#pragma unroll
      for (int j = 0; j < OW; ++j) H[base + j] += acc2[j];
    }
  }
}

// ---------------- pool + final MLP ----------------
__global__ void k_pool(const float* __restrict__ h, const int* __restrict__ batch,
                       unsigned* __restrict__ gmax) {
  __shared__ unsigned lmax[BB * 64];
  for (int i = threadIdx.x; i < BB * 64; i += blockDim.x) lmax[i] = 0x007FFFFFu;
  __syncthreads();
  int total = NN * 64;
  for (int i = blockIdx.x * blockDim.x + threadIdx.x; i < total; i += gridDim.x * blockDim.x) {
    int node = i >> 6, c = i & 63;
    atomicMax(&lmax[(batch[node] << 6) + c], fmap(h[i]));
  }
  __syncthreads();
  for (int i = threadIdx.x; i < BB * 64; i += blockDim.x) atomicMax(&gmax[i], lmax[i]);
}

__global__ void k_final(const unsigned* __restrict__ gmax, const float* __restrict__ w1,
                        const float* __restrict__ b1, const float* __restrict__ w2,
                        const float* __restrict__ b2, float* __restrict__ out) {
  int b = blockIdx.x;
  __shared__ float g[64], hid[64];
  int t = threadIdx.x;
  if (t < 64) {
    float v = funmap(gmax[b * 64 + t]);
    if (v == -INFINITY) v = 0.f;
    g[t] = v;
  }
  __syncthreads();
  if (t < 64) {
    float acc = b1[t];
    for (int c = 0; c < 64; ++c) acc += g[c] * w1[c * 64 + t];
    hid[t] = fmaxf(acc, 0.f);
  }
  __syncthreads();
  if (t < 80) {
    float acc = b2[t];
    for (int c = 0; c < 64; ++c) acc += hid[c] * w2[c * 80 + t];
    out[b * 80 + t] = acc;
  }
}

extern "C" void kernel_launch(void* const* d_in, const int* in_sizes, int n_in,
                              void* d_out, int out_size, void* d_ws, size_t ws_size,
                              hipStream_t stream) {
  const float* x       = (const float*)d_in[0];
  const int*   ei      = (const int*)d_in[1];
  const int*   batch   = (const int*)d_in[2];
  const float* cin_w1  = (const float*)d_in[3];
  const float* cin_b1  = (const float*)d_in[4];
  const float* cin_g1  = (const float*)d_in[5];
  const float* cin_be1 = (const float*)d_in[6];
  const float* cin_w2  = (const float*)d_in[7];
  const float* cin_b2  = (const float*)d_in[8];
  const float* L_w1    = (const float*)d_in[9];
  const float* L_b1    = (const float*)d_in[10];
  const float* L_g1    = (const float*)d_in[11];
  const float* L_be1   = (const float*)d_in[12];
  const float* L_w2    = (const float*)d_in[13];
  const float* L_b2    = (const float*)d_in[14];
  const float* mlp_w1  = (const float*)d_in[15];
  const float* mlp_b1  = (const float*)d_in[16];
  const float* mlp_w2  = (const float*)d_in[17];
  const float* mlp_b2  = (const float*)d_in[18];

  char* ws = (char*)d_ws;
  size_t off = 0;
  auto alloc = [&](size_t bytes) -> void* {
    void* p = ws + off;
    off = (off + bytes + 255) & ~(size_t)255;
    return p;
  };
  float*    A       = (float*)alloc((size_t)NN * 64 * 4);
  float*    h       = (float*)alloc((size_t)NN * 64 * 4);
  int*      rowptr  = (int*)alloc((size_t)(NN + 1) * 4);
  int*      cursor  = (int*)alloc((size_t)NN * 4);   // counts, then write cursors
  int*      adjsrc  = (int*)alloc((size_t)EE * 4);
  int*      partial = (int*)alloc(NSCAN * 4);
  int*      poffs   = (int*)alloc(128 * 4);
  float*    Sbuf    = (float*)alloc((size_t)4 * 4160 * 4);  // per layer: S(F*F) + cs(F)
  float*    ab      = (float*)alloc((size_t)4 * 256 * 4);
  unsigned* gmax    = (unsigned*)alloc((size_t)BB * 64 * 4);
  (void)ws_size; (void)in_sizes; (void)n_in; (void)out_size;

  const int* srcp = ei;
  const int* dstp = ei + EE;

  // CSR build
  hipMemsetAsync(cursor, 0, (size_t)NN * 4, stream);
  hipMemsetAsync(Sbuf, 0, (size_t)4 * 4160 * 4, stream);
  k_hist<<<(EE + 255) / 256, 256, 0, stream>>>(dstp, cursor);
  k_scan1<<<NSCAN, 1024, 0, stream>>>(cursor, rowptr, partial);
  k_scan2<<<1, 128, 0, stream>>>(partial, poffs, gmax);
  k_scan3<<<NSCAN, 1024, 0, stream>>>(rowptr, poffs, cursor);
  k_scatter<<<(EE + 255) / 256, 256, 0, stream>>>(srcp, dstp, cursor, adjsrc);

  const int NB64 = (NN + 63) / 64;  // 1563

  // Layer 0: x[N,6] -> h[N,64], h = relu(...)
  {
    float* S = Sbuf + 0 * 4160;
    float* cs = S + 6 * 6;
    float* ab0 = ab + 0 * 256;
    k_agg<6, 0><<<NN / 4, 256, 0, stream>>>(x, rowptr, adjsrc, A);
    k_ata<6><<<128, 256, 0, stream>>>(A, S, cs);
    k_bnprep<6, 12><<<12, 64, 0, stream>>>(S, cs, cin_w1, cin_b1, cin_g1, cin_be1, ab0);
    k_layer<6, 12, 64, 0><<<NB64, 256, 0, stream>>>(A, cin_w1, ab0, cin_w2, cin_b2, h);
  }

  // Layers 1..3: h += MLP(BN(agg(relu(h)) @ W1)) @ W2
  for (int i = 0; i < 3; ++i) {
    float* S = Sbuf + (size_t)(i + 1) * 4160;
    float* cs = S + 64 * 64;
    float* abi = ab + (size_t)(i + 1) * 256;
    k_agg<64, 1><<<NN / 4, 256, 0, stream>>>(h, rowptr, adjsrc, A);
    k_ata<64><<<512, 256, 0, stream>>>(A, S, cs);
    k_bnprep<64, 128><<<128, 64, 0, stream>>>(S, cs, L_w1 + (size_t)i * 64 * 128,
                                              L_b1 + i * 128, L_g1 + i * 128,
                                              L_be1 + i * 128, abi);
    k_layer<64, 128, 64, 1><<<NB64, 256, 0, stream>>>(A, L_w1 + (size_t)i * 64 * 128, abi,
                                                      L_w2 + (size_t)i * 128 * 64,
                                                      L_b2 + i * 64, h);
  }

  // Global max pool + final MLP
  k_pool<<<128, 256, 0, stream>>>(h, batch, gmax);
  k_final<<<BB, 128, 0, stream>>>(gmax, mlp_w1, mlp_b1, mlp_w2, mlp_b2, (float*)d_out);
}